// Round 1
// baseline (264.149 us; speedup 1.0000x reference)
//
#include <hip/hip_runtime.h>
#include <hip/hip_bf16.h>
#include <stdint.h>

// Problem constants (GroupedQueryAttention: B=2,S=2048,D=1024,H=16,KVH=4)
#define B_    2
#define S_    2048
#define D_    1024
#define H_    16
#define KVH_  4
#define HD_   64
#define REP_  4
#define SCALE_ 0.125f
#define BS_   (B_ * S_)        // 4096 tokens
#define KVD_  (KVH_ * HD_)     // 256
#define KVD2_ (2 * KVD_)       // 512 (K and V concatenated)

typedef unsigned short u16;
typedef short s16x8 __attribute__((ext_vector_type(8)));
typedef float f32x4 __attribute__((ext_vector_type(4)));

typedef const __attribute__((address_space(1))) void* gvp;
typedef __attribute__((address_space(3))) void* lvp;

__device__ __forceinline__ u16 f2b(float f) {  // RNE f32->bf16 (finite inputs)
  uint32_t u = __float_as_uint(f);
  u += 0x7fffu + ((u >> 16) & 1u);
  return (u16)(u >> 16);
}

// ---------------- f32 -> bf16 conversion, x4 vectorized ----------------
__global__ void cvt_kernel(const float* __restrict__ in, u16* __restrict__ out, int n4) {
  int i = blockIdx.x * blockDim.x + threadIdx.x;
  if (i >= n4) return;
  const float4 v = reinterpret_cast<const float4*>(in)[i];
  uint2 o;
  o.x = (uint32_t)f2b(v.x) | ((uint32_t)f2b(v.y) << 16);
  o.y = (uint32_t)f2b(v.z) | ((uint32_t)f2b(v.w) << 16);
  reinterpret_cast<uint2*>(out)[i] = o;
}

// ---------------- bf16 GEMM, C = A(MxK) * B(NxK)^T  (both K-contiguous) ----------------
// 128x128 tile, BK=32, 4 waves, 4x4 16x16x32 MFMA acc per wave. m97 structure.
template <int OUT_BF16>
__global__ __launch_bounds__(256) void gemm_bt(const u16* __restrict__ A,
                                               const u16* __restrict__ Bw,
                                               void* __restrict__ Cout,
                                               int M, int N, int K) {
  __shared__ u16 As[128 * 32];
  __shared__ u16 Bs[128 * 32];
  const int tid = threadIdx.x;
  const int lane = tid & 63;
  const int wid = tid >> 6;
  const int l16 = lane & 15;
  const int kq = lane >> 4;
  const int bm = blockIdx.y * 128;
  const int bn = blockIdx.x * 128;
  const int wr = (wid >> 1) * 64;
  const int wc = (wid & 1) * 64;

  f32x4 acc[4][4] = {};

  for (int kt = 0; kt < K; kt += 32) {
    __syncthreads();
#pragma unroll
    for (int i = 0; i < 2; ++i) {
      const int e = (i * 256 + tid) * 8;   // element index in [128][32] tile
      const int row = e >> 5;
      const int col = e & 31;
      __builtin_amdgcn_global_load_lds((gvp)(A + (size_t)(bm + row) * K + kt + col),
                                       (lvp)(&As[e]), 16, 0, 0);
      __builtin_amdgcn_global_load_lds((gvp)(Bw + (size_t)(bn + row) * K + kt + col),
                                       (lvp)(&Bs[e]), 16, 0, 0);
    }
    __syncthreads();

    s16x8 af[4], bfr[4];
#pragma unroll
    for (int m = 0; m < 4; ++m)
      af[m] = *reinterpret_cast<const s16x8*>(&As[(wr + m * 16 + l16) * 32 + kq * 8]);
#pragma unroll
    for (int n = 0; n < 4; ++n)
      bfr[n] = *reinterpret_cast<const s16x8*>(&Bs[(wc + n * 16 + l16) * 32 + kq * 8]);
#pragma unroll
    for (int m = 0; m < 4; ++m)
#pragma unroll
      for (int n = 0; n < 4; ++n)
        acc[m][n] = __builtin_amdgcn_mfma_f32_16x16x32_bf16(af[m], bfr[n], acc[m][n], 0, 0, 0);
  }

  // C/D layout: col = lane&15, row = (lane>>4)*4 + r  (m89-verified)
#pragma unroll
  for (int m = 0; m < 4; ++m) {
    const int row0 = bm + wr + m * 16 + kq * 4;
#pragma unroll
    for (int n = 0; n < 4; ++n) {
      const int col = bn + wc + n * 16 + l16;
#pragma unroll
      for (int r = 0; r < 4; ++r) {
        if (OUT_BF16) {
          ((u16*)Cout)[(size_t)(row0 + r) * N + col] = f2b(acc[m][n][r]);
        } else {
          ((float*)Cout)[(size_t)(row0 + r) * N + col] = acc[m][n][r];
        }
      }
    }
  }
}

// ---------------- flash attention (GQA) ----------------
// grid: (S/64, B*H). 256 thr = 4 waves; wave w owns q rows [q0+w*16, +16).
// KV tile = 64 rows staged in LDS (K row-major, V transposed).
__global__ __launch_bounds__(256) void attn_kernel(const u16* __restrict__ Q,
                                                   const u16* __restrict__ KV,
                                                   const int* __restrict__ mask,
                                                   u16* __restrict__ O) {
  __shared__ u16 Ks[64 * 64];
  __shared__ u16 Vt[64 * 64];          // Vt[d][kv]
  __shared__ u16 Ps[4][16 * 64];       // per-wave P tile
  __shared__ float smask[64];

  const int tid = threadIdx.x;
  const int lane = tid & 63;
  const int wid = tid >> 6;
  const int l16 = lane & 15;
  const int kq = lane >> 4;
  const int bh = blockIdx.y;
  const int b = bh >> 4;               // / H
  const int h = bh & 15;
  const int g = h >> 2;                // / REP
  const int q0 = blockIdx.x * 64 + wid * 16;

  // Q fragments for this wave's 16 rows (A-frag: row=l16, k=kq*8+j)
  s16x8 qf[2];
  {
    const u16* qp = Q + (size_t)(b * S_ + q0 + l16) * D_ + h * HD_ + kq * 8;
    qf[0] = *reinterpret_cast<const s16x8*>(qp);
    qf[1] = *reinterpret_cast<const s16x8*>(qp + 32);
  }

  float m_run[4], l_run[4];
  f32x4 acc_o[4] = {};
#pragma unroll
  for (int r = 0; r < 4; ++r) { m_run[r] = -1e30f; l_run[r] = 0.f; }

  for (int kv0 = 0; kv0 < S_; kv0 += 64) {
    __syncthreads();
    // stage K tile (64x64) via global_load_lds
#pragma unroll
    for (int i = 0; i < 2; ++i) {
      const int e = (i * 256 + tid) * 8;
      const int row = e >> 6;
      const int col = e & 63;
      __builtin_amdgcn_global_load_lds(
          (gvp)(KV + (size_t)(b * S_ + kv0 + row) * KVD2_ + g * HD_ + col),
          (lvp)(&Ks[e]), 16, 0, 0);
    }
    // stage V transposed: thread reads 16 contiguous bf16, scatters into Vt[d][kv]
    {
      const int kvr = tid >> 2;
      const int dc = (tid & 3) * 16;
      const u16* gv = KV + (size_t)(b * S_ + kv0 + kvr) * KVD2_ + KVD_ + g * HD_ + dc;
      const uint4 va = reinterpret_cast<const uint4*>(gv)[0];
      const uint4 vb = reinterpret_cast<const uint4*>(gv)[1];
      const uint32_t vv[8] = {va.x, va.y, va.z, va.w, vb.x, vb.y, vb.z, vb.w};
#pragma unroll
      for (int j = 0; j < 8; ++j) {
        Vt[(dc + 2 * j) * 64 + kvr] = (u16)(vv[j] & 0xffffu);
        Vt[(dc + 2 * j + 1) * 64 + kvr] = (u16)(vv[j] >> 16);
      }
    }
    if (tid < 64) smask[tid] = mask[b * S_ + kv0 + tid] ? 0.f : -1e30f;
    __syncthreads();

    // scores: 16x64 = QK^T (BT-GEMM)
    f32x4 sc[4];
#pragma unroll
    for (int n = 0; n < 4; ++n) {
      f32x4 s = {0.f, 0.f, 0.f, 0.f};
#pragma unroll
      for (int c = 0; c < 2; ++c) {
        const s16x8 kf =
            *reinterpret_cast<const s16x8*>(&Ks[(n * 16 + l16) * 64 + c * 32 + kq * 8]);
        s = __builtin_amdgcn_mfma_f32_16x16x32_bf16(qf[c], kf, s, 0, 0, 0);
      }
      sc[n] = s;
    }

    // scale + mask, tile row-max
    float tmax[4];
#pragma unroll
    for (int r = 0; r < 4; ++r) tmax[r] = -1e30f;
#pragma unroll
    for (int n = 0; n < 4; ++n) {
      const float mk = smask[n * 16 + l16];
#pragma unroll
      for (int r = 0; r < 4; ++r) {
        sc[n][r] = sc[n][r] * SCALE_ + mk;
        tmax[r] = fmaxf(tmax[r], sc[n][r]);
      }
    }
#pragma unroll
    for (int off = 1; off < 16; off <<= 1)
#pragma unroll
      for (int r = 0; r < 4; ++r) tmax[r] = fmaxf(tmax[r], __shfl_xor(tmax[r], off));

    float fac[4], rsum[4];
#pragma unroll
    for (int r = 0; r < 4; ++r) {
      const float mnew = fmaxf(m_run[r], tmax[r]);
      fac[r] = __expf(m_run[r] - mnew);
      m_run[r] = mnew;
      rsum[r] = 0.f;
    }
#pragma unroll
    for (int n = 0; n < 4; ++n)
#pragma unroll
      for (int r = 0; r < 4; ++r) {
        const float p = __expf(sc[n][r] - m_run[r]);
        sc[n][r] = p;
        rsum[r] += p;
      }
#pragma unroll
    for (int off = 1; off < 16; off <<= 1)
#pragma unroll
      for (int r = 0; r < 4; ++r) rsum[r] += __shfl_xor(rsum[r], off);
#pragma unroll
    for (int r = 0; r < 4; ++r) l_run[r] = l_run[r] * fac[r] + rsum[r];
#pragma unroll
    for (int n = 0; n < 4; ++n)
#pragma unroll
      for (int r = 0; r < 4; ++r) acc_o[n][r] *= fac[r];

    // P -> LDS (C-layout rows -> A-layout rows), wave-private buffer, no barrier
    u16* ps = &Ps[wid][0];
#pragma unroll
    for (int n = 0; n < 4; ++n)
#pragma unroll
      for (int r = 0; r < 4; ++r)
        ps[(kq * 4 + r) * 64 + n * 16 + l16] = f2b(sc[n][r]);

    s16x8 pf[2];
    pf[0] = *reinterpret_cast<const s16x8*>(&ps[l16 * 64 + kq * 8]);
    pf[1] = *reinterpret_cast<const s16x8*>(&ps[l16 * 64 + 32 + kq * 8]);

    // O += P * V   (B-frag from Vt: V[kv][d] at Vt[d][kv])
#pragma unroll
    for (int n = 0; n < 4; ++n) {
#pragma unroll
      for (int c = 0; c < 2; ++c) {
        const s16x8 vf =
            *reinterpret_cast<const s16x8*>(&Vt[(n * 16 + l16) * 64 + c * 32 + kq * 8]);
        acc_o[n] = __builtin_amdgcn_mfma_f32_16x16x32_bf16(pf[c], vf, acc_o[n], 0, 0, 0);
      }
    }
  }

  // normalize + store attn output (bf16, token-major [BS][D])
#pragma unroll
  for (int n = 0; n < 4; ++n) {
    const int col = h * HD_ + n * 16 + l16;
#pragma unroll
    for (int r = 0; r < 4; ++r) {
      const int row = q0 + kq * 4 + r;
      O[(size_t)(b * S_ + row) * D_ + col] = f2b(acc_o[n][r] / l_run[r]);
    }
  }
}

// ---------------- launch ----------------
extern "C" void kernel_launch(void* const* d_in, const int* in_sizes, int n_in,
                              void* d_out, int out_size, void* d_ws, size_t ws_size,
                              hipStream_t stream) {
  const float* x = (const float*)d_in[0];
  const int* mask = (const int*)d_in[1];
  const float* Wq = (const float*)d_in[2];
  const float* Wk = (const float*)d_in[3];
  const float* Wv = (const float*)d_in[4];
  const float* Wo = (const float*)d_in[5];

  char* w = (char*)d_ws;
  u16* xb = (u16*)w;   w += (size_t)BS_ * D_ * 2;
  u16* Wqb = (u16*)w;  w += (size_t)D_ * D_ * 2;
  u16* Wkvb = (u16*)w; w += (size_t)KVD2_ * D_ * 2;   // Wk rows then Wv rows: 512 x 1024
  u16* Wob = (u16*)w;  w += (size_t)D_ * D_ * 2;
  u16* Qw = (u16*)w;   w += (size_t)BS_ * D_ * 2;
  u16* KVw = (u16*)w;  w += (size_t)BS_ * KVD2_ * 2;  // [token][ K(256) | V(256) ]
  u16* AOw = (u16*)w;  w += (size_t)BS_ * D_ * 2;

  auto cvt = [&](const float* src, u16* dst, int n) {
    int n4 = n / 4;
    cvt_kernel<<<dim3((n4 + 255) / 256), dim3(256), 0, stream>>>(src, dst, n4);
  };
  cvt(x, xb, BS_ * D_);
  cvt(Wq, Wqb, D_ * D_);
  cvt(Wk, Wkvb, KVD_ * D_);
  cvt(Wv, Wkvb + (size_t)KVD_ * D_, KVD_ * D_);
  cvt(Wo, Wob, D_ * D_);

  // Q projection: (4096x1024) = xb * Wq^T
  gemm_bt<1><<<dim3(D_ / 128, BS_ / 128), dim3(256), 0, stream>>>(xb, Wqb, Qw, BS_, D_, D_);
  // fused K|V projection: (4096x512)
  gemm_bt<1><<<dim3(KVD2_ / 128, BS_ / 128), dim3(256), 0, stream>>>(xb, Wkvb, KVw, BS_, KVD2_, D_);
  // attention
  attn_kernel<<<dim3(S_ / 64, B_ * H_), dim3(256), 0, stream>>>(Qw, KVw, mask, AOw);
  // output projection -> fp32 d_out
  gemm_bt<0><<<dim3(D_ / 128, BS_ / 128), dim3(256), 0, stream>>>(AOw, Wob, (float*)d_out, BS_, D_, D_);
}

// Round 3
// 236.154 us; speedup vs baseline: 1.1185x; 1.1185x over previous
//
#include <hip/hip_runtime.h>
#include <hip/hip_bf16.h>
#include <stdint.h>

// Problem constants (GroupedQueryAttention: B=2,S=2048,D=1024,H=16,KVH=4)
#define B_    2
#define S_    2048
#define D_    1024
#define H_    16
#define KVH_  4
#define HD_   64
#define REP_  4
#define SCALE_ 0.125f
#define BS_   (B_ * S_)        // 4096 tokens
#define KVD_  (KVH_ * HD_)     // 256
#define KVD2_ (2 * KVD_)       // 512 (K and V concatenated)

typedef unsigned short u16;
typedef short s16x8 __attribute__((ext_vector_type(8)));
typedef float f32x4 __attribute__((ext_vector_type(4)));

typedef const __attribute__((address_space(1))) void* gvp;
typedef __attribute__((address_space(3))) void* lvp;

__device__ __forceinline__ u16 f2b(float f) {  // RNE f32->bf16 (finite inputs)
  uint32_t u = __float_as_uint(f);
  u += 0x7fffu + ((u >> 16) & 1u);
  return (u16)(u >> 16);
}

// XOR swizzle for 64-elem-wide bf16 LDS rows (128B = 8 x 16B slots).
// slot' = slot ^ (row&7) ^ ((row>>3)&7). Two-term XOR so that BOTH
// low-row-bit-varying reads (l16) and high-row-bit-varying writes (d += 16)
// spread across slots. Involution per row -> write/read must both apply it.
__device__ __forceinline__ int swz64(int row, int slot) {
  return slot ^ (row & 7) ^ ((row >> 3) & 7);
}
__device__ __forceinline__ const s16x8* frag64(const u16* base, int row, int slot) {
  return reinterpret_cast<const s16x8*>(base + row * 64 + swz64(row, slot) * 8);
}

// ---------------- f32 -> bf16 conversion, x4 vectorized ----------------
__global__ void cvt_kernel(const float* __restrict__ in, u16* __restrict__ out, int n4) {
  int i = blockIdx.x * blockDim.x + threadIdx.x;
  if (i >= n4) return;
  const float4 v = reinterpret_cast<const float4*>(in)[i];
  uint2 o;
  o.x = (uint32_t)f2b(v.x) | ((uint32_t)f2b(v.y) << 16);
  o.y = (uint32_t)f2b(v.z) | ((uint32_t)f2b(v.w) << 16);
  reinterpret_cast<uint2*>(out)[i] = o;
}

// ---------------- bf16 GEMM, C = A(MxK) * B(NxK)^T  (both K-contiguous) ----------------
// 128x128 tile, BK=32, 4 waves, 4x4 16x16x32 MFMA acc per wave. m97 structure.
template <int OUT_BF16>
__global__ __launch_bounds__(256) void gemm_bt(const u16* __restrict__ A,
                                               const u16* __restrict__ Bw,
                                               void* __restrict__ Cout,
                                               int M, int N, int K) {
  __shared__ u16 As[128 * 32];
  __shared__ u16 Bs[128 * 32];
  const int tid = threadIdx.x;
  const int lane = tid & 63;
  const int wid = tid >> 6;
  const int l16 = lane & 15;
  const int kq = lane >> 4;
  const int bm = blockIdx.y * 128;
  const int bn = blockIdx.x * 128;
  const int wr = (wid >> 1) * 64;
  const int wc = (wid & 1) * 64;

  f32x4 acc[4][4] = {};

  for (int kt = 0; kt < K; kt += 32) {
    __syncthreads();
#pragma unroll
    for (int i = 0; i < 2; ++i) {
      const int e = (i * 256 + tid) * 8;   // element index in [128][32] tile
      const int row = e >> 5;
      const int col = e & 31;
      __builtin_amdgcn_global_load_lds((gvp)(A + (size_t)(bm + row) * K + kt + col),
                                       (lvp)(&As[e]), 16, 0, 0);
      __builtin_amdgcn_global_load_lds((gvp)(Bw + (size_t)(bn + row) * K + kt + col),
                                       (lvp)(&Bs[e]), 16, 0, 0);
    }
    __syncthreads();

    s16x8 af[4], bfr[4];
#pragma unroll
    for (int m = 0; m < 4; ++m)
      af[m] = *reinterpret_cast<const s16x8*>(&As[(wr + m * 16 + l16) * 32 + kq * 8]);
#pragma unroll
    for (int n = 0; n < 4; ++n)
      bfr[n] = *reinterpret_cast<const s16x8*>(&Bs[(wc + n * 16 + l16) * 32 + kq * 8]);
#pragma unroll
    for (int m = 0; m < 4; ++m)
#pragma unroll
      for (int n = 0; n < 4; ++n)
        acc[m][n] = __builtin_amdgcn_mfma_f32_16x16x32_bf16(af[m], bfr[n], acc[m][n], 0, 0, 0);
  }

  // C/D layout: col = lane&15, row = (lane>>4)*4 + r  (m89-verified)
#pragma unroll
  for (int m = 0; m < 4; ++m) {
    const int row0 = bm + wr + m * 16 + kq * 4;
#pragma unroll
    for (int n = 0; n < 4; ++n) {
      const int col = bn + wc + n * 16 + l16;
#pragma unroll
      for (int r = 0; r < 4; ++r) {
        if (OUT_BF16) {
          ((u16*)Cout)[(size_t)(row0 + r) * N + col] = f2b(acc[m][n][r]);
        } else {
          ((float*)Cout)[(size_t)(row0 + r) * N + col] = acc[m][n][r];
        }
      }
    }
  }
}

// ---------------- flash attention (GQA) ----------------
// grid: (S/64, B*H). 256 thr = 4 waves; wave w owns q rows [q0+w*16, +16).
// KV tile = 64 rows staged in LDS (K row-major swizzled, V transposed swizzled).
__global__ __launch_bounds__(256) void attn_kernel(const u16* __restrict__ Q,
                                                   const u16* __restrict__ KV,
                                                   const int* __restrict__ mask,
                                                   u16* __restrict__ O) {
  __shared__ u16 Ks[64 * 64];
  __shared__ u16 Vt[64 * 64];          // Vt[d][kv], slot-swizzled
  __shared__ u16 Ps[4][16 * 64];       // per-wave P tile, slot-swizzled
  __shared__ float smask[64];

  const int tid = threadIdx.x;
  const int lane = tid & 63;
  const int wid = tid >> 6;
  const int l16 = lane & 15;
  const int kq = lane >> 4;
  const int bh = blockIdx.y;
  const int b = bh >> 4;               // / H
  const int h = bh & 15;
  const int g = h >> 2;                // / REP
  const int q0 = blockIdx.x * 64 + wid * 16;

  // Q fragments for this wave's 16 rows (A-frag: row=l16, k=kq*8+j)
  s16x8 qf[2];
  {
    const u16* qp = Q + (size_t)(b * S_ + q0 + l16) * D_ + h * HD_ + kq * 8;
    qf[0] = *reinterpret_cast<const s16x8*>(qp);
    qf[1] = *reinterpret_cast<const s16x8*>(qp + 32);
  }

  float m_run[4], l_run[4];
  f32x4 acc_o[4] = {};
#pragma unroll
  for (int r = 0; r < 4; ++r) { m_run[r] = -1e30f; l_run[r] = 0.f; }

  for (int kv0 = 0; kv0 < S_; kv0 += 64) {
    __syncthreads();
    // stage K tile (64x64) via global_load_lds: LDS dest linear, SOURCE
    // 16B-chunk pre-swizzled so that swizzled reads see the right data.
#pragma unroll
    for (int i = 0; i < 2; ++i) {
      const int e = (i * 256 + tid) * 8;
      const int row = e >> 6;
      const int scol = swz64(row, (e & 63) >> 3) * 8;
      __builtin_amdgcn_global_load_lds(
          (gvp)(KV + (size_t)(b * S_ + kv0 + row) * KVD2_ + g * HD_ + scol),
          (lvp)(&Ks[e]), 16, 0, 0);
    }
    // stage V transposed: thread reads 16 contiguous bf16 of one V row,
    // scatters into swizzled Vt[d][kv]
    {
      const int kvr = tid >> 2;
      const int dc = (tid & 3) * 16;
      const u16* gv = KV + (size_t)(b * S_ + kv0 + kvr) * KVD2_ + KVD_ + g * HD_ + dc;
      const uint4 va = reinterpret_cast<const uint4*>(gv)[0];
      const uint4 vb = reinterpret_cast<const uint4*>(gv)[1];
      const uint32_t vv[8] = {va.x, va.y, va.z, va.w, vb.x, vb.y, vb.z, vb.w};
      const int sl = kvr >> 3;         // kv slot
      const int wv = kvr & 7;          // within-slot
#pragma unroll
      for (int j = 0; j < 8; ++j) {
        const int d0 = dc + 2 * j;
        const int d1 = d0 + 1;
        Vt[d0 * 64 + swz64(d0, sl) * 8 + wv] = (u16)(vv[j] & 0xffffu);
        Vt[d1 * 64 + swz64(d1, sl) * 8 + wv] = (u16)(vv[j] >> 16);
      }
    }
    if (tid < 64) smask[tid] = mask[b * S_ + kv0 + tid] ? 0.f : -1e30f;
    __syncthreads();

    // scores: 16x64 = QK^T (BT-GEMM), K-frags via swizzled reads
    f32x4 sc[4];
#pragma unroll
    for (int n = 0; n < 4; ++n) {
      f32x4 s = {0.f, 0.f, 0.f, 0.f};
#pragma unroll
      for (int c = 0; c < 2; ++c) {
        const s16x8 kf = *frag64(Ks, n * 16 + l16, c * 4 + kq);
        s = __builtin_amdgcn_mfma_f32_16x16x32_bf16(qf[c], kf, s, 0, 0, 0);
      }
      sc[n] = s;
    }

    // scale + mask, tile row-max
    float tmax[4];
#pragma unroll
    for (int r = 0; r < 4; ++r) tmax[r] = -1e30f;
#pragma unroll
    for (int n = 0; n < 4; ++n) {
      const float mk = smask[n * 16 + l16];
#pragma unroll
      for (int r = 0; r < 4; ++r) {
        sc[n][r] = sc[n][r] * SCALE_ + mk;
        tmax[r] = fmaxf(tmax[r], sc[n][r]);
      }
    }
#pragma unroll
    for (int off = 1; off < 16; off <<= 1)
#pragma unroll
      for (int r = 0; r < 4; ++r) tmax[r] = fmaxf(tmax[r], __shfl_xor(tmax[r], off));

    float fac[4], rsum[4];
#pragma unroll
    for (int r = 0; r < 4; ++r) {
      const float mnew = fmaxf(m_run[r], tmax[r]);
      fac[r] = __expf(m_run[r] - mnew);
      m_run[r] = mnew;
      rsum[r] = 0.f;
    }
#pragma unroll
    for (int n = 0; n < 4; ++n)
#pragma unroll
      for (int r = 0; r < 4; ++r) {
        const float p = __expf(sc[n][r] - m_run[r]);
        sc[n][r] = p;
        rsum[r] += p;
      }
#pragma unroll
    for (int off = 1; off < 16; off <<= 1)
#pragma unroll
      for (int r = 0; r < 4; ++r) rsum[r] += __shfl_xor(rsum[r], off);
#pragma unroll
    for (int r = 0; r < 4; ++r) l_run[r] = l_run[r] * fac[r] + rsum[r];
#pragma unroll
    for (int n = 0; n < 4; ++n)
#pragma unroll
      for (int r = 0; r < 4; ++r) acc_o[n][r] *= fac[r];

    // P -> LDS (C-layout rows -> A-layout rows), wave-private swizzled buffer
    u16* ps = &Ps[wid][0];
#pragma unroll
    for (int n = 0; n < 4; ++n)
#pragma unroll
      for (int r = 0; r < 4; ++r) {
        const int prow = kq * 4 + r;
        const int pslot = n * 2 + (l16 >> 3);
        ps[prow * 64 + swz64(prow, pslot) * 8 + (l16 & 7)] = f2b(sc[n][r]);
      }

    s16x8 pf[2];
    pf[0] = *frag64(ps, l16, kq);
    pf[1] = *frag64(ps, l16, 4 + kq);

    // O += P * V   (B-frag from swizzled Vt)
#pragma unroll
    for (int n = 0; n < 4; ++n) {
#pragma unroll
      for (int c = 0; c < 2; ++c) {
        const s16x8 vf = *frag64(Vt, n * 16 + l16, c * 4 + kq);
        acc_o[n] = __builtin_amdgcn_mfma_f32_16x16x32_bf16(pf[c], vf, acc_o[n], 0, 0, 0);
      }
    }
  }

  // normalize + store attn output (bf16, token-major [BS][D])
#pragma unroll
  for (int n = 0; n < 4; ++n) {
    const int col = h * HD_ + n * 16 + l16;
#pragma unroll
    for (int r = 0; r < 4; ++r) {
      const int row = q0 + kq * 4 + r;
      O[(size_t)(b * S_ + row) * D_ + col] = f2b(acc_o[n][r] / l_run[r]);
    }
  }
}

// ---------------- launch ----------------
extern "C" void kernel_launch(void* const* d_in, const int* in_sizes, int n_in,
                              void* d_out, int out_size, void* d_ws, size_t ws_size,
                              hipStream_t stream) {
  const float* x = (const float*)d_in[0];
  const int* mask = (const int*)d_in[1];
  const float* Wq = (const float*)d_in[2];
  const float* Wk = (const float*)d_in[3];
  const float* Wv = (const float*)d_in[4];
  const float* Wo = (const float*)d_in[5];

  char* w = (char*)d_ws;
  u16* xb = (u16*)w;   w += (size_t)BS_ * D_ * 2;
  u16* Wqb = (u16*)w;  w += (size_t)D_ * D_ * 2;
  u16* Wkvb = (u16*)w; w += (size_t)KVD2_ * D_ * 2;   // Wk rows then Wv rows: 512 x 1024
  u16* Wob = (u16*)w;  w += (size_t)D_ * D_ * 2;
  u16* Qw = (u16*)w;   w += (size_t)BS_ * D_ * 2;
  u16* KVw = (u16*)w;  w += (size_t)BS_ * KVD2_ * 2;  // [token][ K(256) | V(256) ]
  u16* AOw = (u16*)w;  w += (size_t)BS_ * D_ * 2;

  auto cvt = [&](const float* src, u16* dst, int n) {
    int n4 = n / 4;
    cvt_kernel<<<dim3((n4 + 255) / 256), dim3(256), 0, stream>>>(src, dst, n4);
  };
  cvt(x, xb, BS_ * D_);
  cvt(Wq, Wqb, D_ * D_);
  cvt(Wk, Wkvb, KVD_ * D_);
  cvt(Wv, Wkvb + (size_t)KVD_ * D_, KVD_ * D_);
  cvt(Wo, Wob, D_ * D_);

  // Q projection: (4096x1024) = xb * Wq^T
  gemm_bt<1><<<dim3(D_ / 128, BS_ / 128), dim3(256), 0, stream>>>(xb, Wqb, Qw, BS_, D_, D_);
  // fused K|V projection: (4096x512)
  gemm_bt<1><<<dim3(KVD2_ / 128, BS_ / 128), dim3(256), 0, stream>>>(xb, Wkvb, KVw, BS_, KVD2_, D_);
  // attention
  attn_kernel<<<dim3(S_ / 64, B_ * H_), dim3(256), 0, stream>>>(Qw, KVw, mask, AOw);
  // output projection -> fp32 d_out
  gemm_bt<0><<<dim3(D_ / 128, BS_ / 128), dim3(256), 0, stream>>>(AOw, Wob, (float*)d_out, BS_, D_, D_);
}

// Round 5
// 189.158 us; speedup vs baseline: 1.3964x; 1.2484x over previous
//
#include <hip/hip_runtime.h>
#include <hip/hip_bf16.h>
#include <stdint.h>

// Problem constants (GroupedQueryAttention: B=2,S=2048,D=1024,H=16,KVH=4)
#define B_    2
#define S_    2048
#define D_    1024
#define H_    16
#define KVH_  4
#define HD_   64
#define REP_  4
#define SCALE_ 0.125f
#define BS_   (B_ * S_)        // 4096 tokens
#define KVD_  (KVH_ * HD_)     // 256
#define KVD2_ (2 * KVD_)       // 512 (K and V concatenated)

typedef unsigned short u16;
typedef short s16x8 __attribute__((ext_vector_type(8)));
typedef float f32x4 __attribute__((ext_vector_type(4)));

typedef const __attribute__((address_space(1))) void* gvp;
typedef __attribute__((address_space(3))) void* lvp;

__device__ __forceinline__ u16 f2b(float f) {  // RNE f32->bf16 (finite inputs)
  uint32_t u = __float_as_uint(f);
  u += 0x7fffu + ((u >> 16) & 1u);
  return (u16)(u >> 16);
}

// XOR swizzle for 64-elem-wide bf16 LDS rows (128B = 8 x 16B slots).
__device__ __forceinline__ int swz64(int row, int slot) {
  return slot ^ (row & 7) ^ ((row >> 3) & 7);
}
__device__ __forceinline__ const s16x8* frag64(const u16* base, int row, int slot) {
  return reinterpret_cast<const s16x8*>(base + row * 64 + swz64(row, slot) * 8);
}

// ---------------- f32 -> bf16 conversion, x4 vectorized ----------------
__global__ void cvt_kernel(const float* __restrict__ in, u16* __restrict__ out, int n4) {
  int i = blockIdx.x * blockDim.x + threadIdx.x;
  if (i >= n4) return;
  const float4 v = reinterpret_cast<const float4*>(in)[i];
  uint2 o;
  o.x = (uint32_t)f2b(v.x) | ((uint32_t)f2b(v.y) << 16);
  o.y = (uint32_t)f2b(v.z) | ((uint32_t)f2b(v.w) << 16);
  reinterpret_cast<uint2*>(out)[i] = o;
}

// ---------------- bf16 GEMM, C = A(MxK) * B(NxK)^T  (both K-contiguous) ----------------
// 128x128 tile, BK=32, 4 waves, 4x4 16x16x32 MFMA acc per wave. m97 structure.
template <int OUT_BF16>
__global__ __launch_bounds__(256) void gemm_bt(const u16* __restrict__ A,
                                               const u16* __restrict__ Bw,
                                               void* __restrict__ Cout,
                                               int M, int N, int K) {
  __shared__ u16 As[128 * 32];
  __shared__ u16 Bs[128 * 32];
  const int tid = threadIdx.x;
  const int lane = tid & 63;
  const int wid = tid >> 6;
  const int l16 = lane & 15;
  const int kq = lane >> 4;
  const int bm = blockIdx.y * 128;
  const int bn = blockIdx.x * 128;
  const int wr = (wid >> 1) * 64;
  const int wc = (wid & 1) * 64;

  f32x4 acc[4][4] = {};

  for (int kt = 0; kt < K; kt += 32) {
    __syncthreads();
#pragma unroll
    for (int i = 0; i < 2; ++i) {
      const int e = (i * 256 + tid) * 8;   // element index in [128][32] tile
      const int row = e >> 5;
      const int col = e & 31;
      __builtin_amdgcn_global_load_lds((gvp)(A + (size_t)(bm + row) * K + kt + col),
                                       (lvp)(&As[e]), 16, 0, 0);
      __builtin_amdgcn_global_load_lds((gvp)(Bw + (size_t)(bn + row) * K + kt + col),
                                       (lvp)(&Bs[e]), 16, 0, 0);
    }
    __syncthreads();

    s16x8 af[4], bfr[4];
#pragma unroll
    for (int m = 0; m < 4; ++m)
      af[m] = *reinterpret_cast<const s16x8*>(&As[(wr + m * 16 + l16) * 32 + kq * 8]);
#pragma unroll
    for (int n = 0; n < 4; ++n)
      bfr[n] = *reinterpret_cast<const s16x8*>(&Bs[(wc + n * 16 + l16) * 32 + kq * 8]);
#pragma unroll
    for (int m = 0; m < 4; ++m)
#pragma unroll
      for (int n = 0; n < 4; ++n)
        acc[m][n] = __builtin_amdgcn_mfma_f32_16x16x32_bf16(af[m], bfr[n], acc[m][n], 0, 0, 0);
  }

  // C/D layout: col = lane&15, row = (lane>>4)*4 + r  (m89-verified)
#pragma unroll
  for (int m = 0; m < 4; ++m) {
    const int row0 = bm + wr + m * 16 + kq * 4;
#pragma unroll
    for (int n = 0; n < 4; ++n) {
      const int col = bn + wc + n * 16 + l16;
#pragma unroll
      for (int r = 0; r < 4; ++r) {
        if (OUT_BF16) {
          ((u16*)Cout)[(size_t)(row0 + r) * N + col] = f2b(acc[m][n][r]);
        } else {
          ((float*)Cout)[(size_t)(row0 + r) * N + col] = acc[m][n][r];
        }
      }
    }
  }
}

// ---------------- flash attention (GQA), swapped-QK^T structure ----------------
// grid: (S/32, B*KVH). 512 thr = 8 waves; wave w handles head g*4+(w&3),
// q rows [q0 + (w>>2)*16, +16). All 8 waves share one K/V staging per tile.
// S^T = mfma(K,Q): lane (kq,l16) holds S^T[kv=n*16+kq*4+r][q=l16] -> softmax
// stats are per-lane scalars; P stays in registers (shfl exchange);
// O^T = mfma(V^T, P).
__global__ __launch_bounds__(512) void attn_kernel(const u16* __restrict__ Q,
                                                   const u16* __restrict__ KV,
                                                   const int* __restrict__ mask,
                                                   u16* __restrict__ O) {
  __shared__ u16 Ks[64 * 64];
  __shared__ u16 Vt[64 * 64];          // Vt[d][kv], slot-swizzled
  __shared__ float smask[64];

  const int tid = threadIdx.x;
  const int lane = tid & 63;
  const int wid = tid >> 6;            // 0..7
  const int l16 = lane & 15;
  const int kq = lane >> 4;            // 0..3
  const int bg = blockIdx.y;
  const int b = bg >> 2;               // / KVH
  const int g = bg & 3;
  const int h = g * REP_ + (wid & 3);
  const int q0 = blockIdx.x * 32 + (wid >> 2) * 16;

  // Q B-frags (rows of Q): lane holds Q[q0+l16][c*32 + kq*8 + j]
  s16x8 qf[2];
  {
    const u16* qp = Q + (size_t)(b * S_ + q0 + l16) * D_ + h * HD_ + kq * 8;
    qf[0] = *reinterpret_cast<const s16x8*>(qp);
    qf[1] = *reinterpret_cast<const s16x8*>(qp + 32);
  }

  float m_run = -1e30f, l_run = 0.f;
  f32x4 acc[4] = {};                   // O^T: lane holds O^T[m*16+kq*4+r][q=l16]
  const float Cs = 0.18033688011112042f;  // SCALE * log2(e)

  for (int kv0 = 0; kv0 < S_; kv0 += 64) {
    __syncthreads();
    // K tile: linear LDS dest, source 16B-chunk pre-swizzled (1 load/thread)
    {
      const int row = tid >> 3;
      const int slot = tid & 7;
      __builtin_amdgcn_global_load_lds(
          (gvp)(KV + (size_t)(b * S_ + kv0 + row) * KVD2_ + g * HD_ + swz64(row, slot) * 8),
          (lvp)(&Ks[tid * 8]), 16, 0, 0);
    }
    // V transposed into swizzled Vt[d][kv] (8 b16 writes/thread)
    {
      const int kvr = tid >> 3;
      const int dc = (tid & 7) * 8;
      const uint4 va = *reinterpret_cast<const uint4*>(
          KV + (size_t)(b * S_ + kv0 + kvr) * KVD2_ + KVD_ + g * HD_ + dc);
      const uint32_t vv[4] = {va.x, va.y, va.z, va.w};
      const int sl = kvr >> 3;
      const int wv = kvr & 7;
#pragma unroll
      for (int j = 0; j < 4; ++j) {
        const int d0 = dc + 2 * j;
        const int d1 = d0 + 1;
        Vt[d0 * 64 + swz64(d0, sl) * 8 + wv] = (u16)(vv[j] & 0xffffu);
        Vt[d1 * 64 + swz64(d1, sl) * 8 + wv] = (u16)(vv[j] >> 16);
      }
    }
    if (tid < 64) smask[tid] = mask[b * S_ + kv0 + tid] ? 0.f : -1e30f;
    __syncthreads();

    // S^T = K·Q^T: sc[n] holds rows n*16+kq*4+r (kv), col l16 (q)
    f32x4 sc[4];
#pragma unroll
    for (int n = 0; n < 4; ++n) {
      f32x4 s = {0.f, 0.f, 0.f, 0.f};
#pragma unroll
      for (int c = 0; c < 2; ++c) {
        const s16x8 kf = *frag64(Ks, n * 16 + l16, c * 4 + kq);
        s = __builtin_amdgcn_mfma_f32_16x16x32_bf16(kf, qf[c], s, 0, 0, 0);
      }
      sc[n] = s;
    }

    // scale + mask in log2 domain; per-lane max over 16 + 2 shfl across kq
    float tm = -1e30f;
#pragma unroll
    for (int n = 0; n < 4; ++n) {
      const f32x4 mk = *reinterpret_cast<const f32x4*>(&smask[n * 16 + kq * 4]);
#pragma unroll
      for (int r = 0; r < 4; ++r) {
        sc[n][r] = sc[n][r] * Cs + mk[r];
        tm = fmaxf(tm, sc[n][r]);
      }
    }
    tm = fmaxf(tm, __shfl_xor(tm, 16));
    tm = fmaxf(tm, __shfl_xor(tm, 32));

    // defer-rescale (T13): only rescale when tile max grew past threshold
    if (!__all(tm <= m_run + 8.0f)) {
      const float mnew = fmaxf(m_run, tm);
      const float fac = exp2f(m_run - mnew);
      m_run = mnew;
      l_run *= fac;
#pragma unroll
      for (int m = 0; m < 4; ++m)
#pragma unroll
        for (int r = 0; r < 4; ++r) acc[m][r] *= fac;
    }

    float rs = 0.f;
#pragma unroll
    for (int n = 0; n < 4; ++n)
#pragma unroll
      for (int r = 0; r < 4; ++r) {
        const float p = exp2f(sc[n][r] - m_run);
        sc[n][r] = p;
        rs += p;
      }
    rs += __shfl_xor(rs, 16);
    rs += __shfl_xor(rs, 32);
    l_run += rs;

    // pack P to bf16 pairs: pk[n][h] = (p[n][2h], p[n][2h+1])
    uint32_t pk[4][2];
#pragma unroll
    for (int n = 0; n < 4; ++n) {
      asm("v_cvt_pk_bf16_f32 %0, %1, %2" : "=v"(pk[n][0]) : "v"(sc[n][0]), "v"(sc[n][1]));
      asm("v_cvt_pk_bf16_f32 %0, %1, %2" : "=v"(pk[n][1]) : "v"(sc[n][2]), "v"(sc[n][3]));
    }
    // exchange: B-frag (rows of P) word w of frag c comes from
    // pk[2c + (kq>>1)][w&1] of lane ((kq&1)*2 + (w>>1))*16 + l16.
    const int srcA = ((kq & 1) * 2) * 16 + l16;
    const int srcB = srcA + 16;
    uint32_t bw[2][4];
#pragma unroll
    for (int c = 0; c < 2; ++c) {
#pragma unroll
      for (int w = 0; w < 4; ++w) {
        const int src = (w < 2) ? srcA : srcB;
        const uint32_t lo = __shfl(pk[2 * c][w & 1], src);
        const uint32_t hi = __shfl(pk[2 * c + 1][w & 1], src);
        bw[c][w] = (kq & 2) ? hi : lo;
      }
    }
    union { uint32_t u[4]; s16x8 v; } pf0, pf1;
#pragma unroll
    for (int w = 0; w < 4; ++w) { pf0.u[w] = bw[0][w]; pf1.u[w] = bw[1][w]; }

    // O^T += V^T · P^T : mfma(Vt-frag, P-row-frag)
#pragma unroll
    for (int m = 0; m < 4; ++m) {
      const s16x8 vf0 = *frag64(Vt, m * 16 + l16, kq);
      const s16x8 vf1 = *frag64(Vt, m * 16 + l16, 4 + kq);
      acc[m] = __builtin_amdgcn_mfma_f32_16x16x32_bf16(vf0, pf0.v, acc[m], 0, 0, 0);
      acc[m] = __builtin_amdgcn_mfma_f32_16x16x32_bf16(vf1, pf1.v, acc[m], 0, 0, 0);
    }
  }

  // normalize + store O^T -> O (bf16, token-major [BS][D]); 4x 8B stores
  const float rl = 1.0f / l_run;
  u16* op = O + (size_t)(b * S_ + q0 + l16) * D_ + h * HD_ + kq * 4;
#pragma unroll
  for (int m = 0; m < 4; ++m) {
    uint2 o;
    o.x = (uint32_t)f2b(acc[m][0] * rl) | ((uint32_t)f2b(acc[m][1] * rl) << 16);
    o.y = (uint32_t)f2b(acc[m][2] * rl) | ((uint32_t)f2b(acc[m][3] * rl) << 16);
    *reinterpret_cast<uint2*>(op + m * 16) = o;
  }
}

// ---------------- launch ----------------
extern "C" void kernel_launch(void* const* d_in, const int* in_sizes, int n_in,
                              void* d_out, int out_size, void* d_ws, size_t ws_size,
                              hipStream_t stream) {
  const float* x = (const float*)d_in[0];
  const int* mask = (const int*)d_in[1];
  const float* Wq = (const float*)d_in[2];
  const float* Wk = (const float*)d_in[3];
  const float* Wv = (const float*)d_in[4];
  const float* Wo = (const float*)d_in[5];

  char* w = (char*)d_ws;
  u16* xb = (u16*)w;   w += (size_t)BS_ * D_ * 2;
  u16* Wqb = (u16*)w;  w += (size_t)D_ * D_ * 2;
  u16* Wkvb = (u16*)w; w += (size_t)KVD2_ * D_ * 2;   // Wk rows then Wv rows: 512 x 1024
  u16* Wob = (u16*)w;  w += (size_t)D_ * D_ * 2;
  u16* Qw = (u16*)w;   w += (size_t)BS_ * D_ * 2;
  u16* KVw = (u16*)w;  w += (size_t)BS_ * KVD2_ * 2;  // [token][ K(256) | V(256) ]
  u16* AOw = (u16*)w;  w += (size_t)BS_ * D_ * 2;

  auto cvt = [&](const float* src, u16* dst, int n) {
    int n4 = n / 4;
    cvt_kernel<<<dim3((n4 + 255) / 256), dim3(256), 0, stream>>>(src, dst, n4);
  };
  cvt(x, xb, BS_ * D_);
  cvt(Wq, Wqb, D_ * D_);
  cvt(Wk, Wkvb, KVD_ * D_);
  cvt(Wv, Wkvb + (size_t)KVD_ * D_, KVD_ * D_);
  cvt(Wo, Wob, D_ * D_);

  // Q projection: (4096x1024) = xb * Wq^T
  gemm_bt<1><<<dim3(D_ / 128, BS_ / 128), dim3(256), 0, stream>>>(xb, Wqb, Qw, BS_, D_, D_);
  // fused K|V projection: (4096x512)
  gemm_bt<1><<<dim3(KVD2_ / 128, BS_ / 128), dim3(256), 0, stream>>>(xb, Wkvb, KVw, BS_, KVD2_, D_);
  // attention: (S/32, B*KVH) blocks of 8 waves
  attn_kernel<<<dim3(S_ / 32, B_ * KVH_), dim3(512), 0, stream>>>(Qw, KVw, mask, AOw);
  // output projection -> fp32 d_out
  gemm_bt<0><<<dim3(D_ / 128, BS_ / 128), dim3(256), 0, stream>>>(AOw, Wob, (float*)d_out, BS_, D_, D_);
}

// Round 6
// 184.248 us; speedup vs baseline: 1.4337x; 1.0266x over previous
//
#include <hip/hip_runtime.h>
#include <hip/hip_bf16.h>
#include <stdint.h>

// Problem constants (GroupedQueryAttention: B=2,S=2048,D=1024,H=16,KVH=4)
#define B_    2
#define S_    2048
#define D_    1024
#define H_    16
#define KVH_  4
#define HD_   64
#define REP_  4
#define SCALE_ 0.125f
#define BS_   (B_ * S_)        // 4096 tokens
#define KVD_  (KVH_ * HD_)     // 256
#define KVD2_ (2 * KVD_)       // 512 (K and V concatenated)
#define NT_   (S_ / 64)        // 32 KV tiles

typedef unsigned short u16;
typedef short s16x8 __attribute__((ext_vector_type(8)));
typedef float f32x4 __attribute__((ext_vector_type(4)));

typedef const __attribute__((address_space(1))) void* gvp;
typedef __attribute__((address_space(3))) void* lvp;

__device__ __forceinline__ u16 f2b(float f) {  // RNE f32->bf16 (finite inputs)
  uint32_t u = __float_as_uint(f);
  u += 0x7fffu + ((u >> 16) & 1u);
  return (u16)(u >> 16);
}

// XOR swizzle for 64-elem-wide bf16 LDS rows (128B = 8 x 16B slots).
__device__ __forceinline__ int swz64(int row, int slot) {
  return slot ^ (row & 7) ^ ((row >> 3) & 7);
}
__device__ __forceinline__ const s16x8* frag64(const u16* base, int row, int slot) {
  return reinterpret_cast<const s16x8*>(base + row * 64 + swz64(row, slot) * 8);
}

// ---------------- f32 -> bf16 conversion, x4 vectorized ----------------
__global__ void cvt_kernel(const float* __restrict__ in, u16* __restrict__ out, int n4) {
  int i = blockIdx.x * blockDim.x + threadIdx.x;
  if (i >= n4) return;
  const float4 v = reinterpret_cast<const float4*>(in)[i];
  uint2 o;
  o.x = (uint32_t)f2b(v.x) | ((uint32_t)f2b(v.y) << 16);
  o.y = (uint32_t)f2b(v.z) | ((uint32_t)f2b(v.w) << 16);
  reinterpret_cast<uint2*>(out)[i] = o;
}

// ---------------- bf16 GEMM, C = A(MxK) * B(NxK)^T  (both K-contiguous) ----------------
// 128x128 tile, BK=32, 4 waves, 4x4 16x16x32 MFMA acc per wave. m97 structure.
template <int OUT_BF16>
__global__ __launch_bounds__(256) void gemm_bt(const u16* __restrict__ A,
                                               const u16* __restrict__ Bw,
                                               void* __restrict__ Cout,
                                               int M, int N, int K) {
  __shared__ u16 As[128 * 32];
  __shared__ u16 Bs[128 * 32];
  const int tid = threadIdx.x;
  const int lane = tid & 63;
  const int wid = tid >> 6;
  const int l16 = lane & 15;
  const int kq = lane >> 4;
  const int bm = blockIdx.y * 128;
  const int bn = blockIdx.x * 128;
  const int wr = (wid >> 1) * 64;
  const int wc = (wid & 1) * 64;

  f32x4 acc[4][4] = {};

  for (int kt = 0; kt < K; kt += 32) {
    __syncthreads();
#pragma unroll
    for (int i = 0; i < 2; ++i) {
      const int e = (i * 256 + tid) * 8;   // element index in [128][32] tile
      const int row = e >> 5;
      const int col = e & 31;
      __builtin_amdgcn_global_load_lds((gvp)(A + (size_t)(bm + row) * K + kt + col),
                                       (lvp)(&As[e]), 16, 0, 0);
      __builtin_amdgcn_global_load_lds((gvp)(Bw + (size_t)(bn + row) * K + kt + col),
                                       (lvp)(&Bs[e]), 16, 0, 0);
    }
    __syncthreads();

    s16x8 af[4], bfr[4];
#pragma unroll
    for (int m = 0; m < 4; ++m)
      af[m] = *reinterpret_cast<const s16x8*>(&As[(wr + m * 16 + l16) * 32 + kq * 8]);
#pragma unroll
    for (int n = 0; n < 4; ++n)
      bfr[n] = *reinterpret_cast<const s16x8*>(&Bs[(wc + n * 16 + l16) * 32 + kq * 8]);
#pragma unroll
    for (int m = 0; m < 4; ++m)
#pragma unroll
      for (int n = 0; n < 4; ++n)
        acc[m][n] = __builtin_amdgcn_mfma_f32_16x16x32_bf16(af[m], bfr[n], acc[m][n], 0, 0, 0);
  }

  // C/D layout: col = lane&15, row = (lane>>4)*4 + r  (m89-verified)
#pragma unroll
  for (int m = 0; m < 4; ++m) {
    const int row0 = bm + wr + m * 16 + kq * 4;
#pragma unroll
    for (int n = 0; n < 4; ++n) {
      const int col = bn + wc + n * 16 + l16;
#pragma unroll
      for (int r = 0; r < 4; ++r) {
        if (OUT_BF16) {
          ((u16*)Cout)[(size_t)(row0 + r) * N + col] = f2b(acc[m][n][r]);
        } else {
          ((float*)Cout)[(size_t)(row0 + r) * N + col] = acc[m][n][r];
        }
      }
    }
  }
}

// ---------------- flash attention (GQA), swapped-QK^T + async dbuf staging ----------------
// grid: (S/32, B*KVH). 512 thr = 8 waves; wave w handles head g*4+(w&3),
// q rows [q0 + (w>>2)*16, +16). All 8 waves share K/V staging (double-buffered).
// Per tile: {issue next-tile V-reg loads + K global_load_lds} -> compute current
// -> {write V regs + mask to next LDS buf} -> barrier. Staging latency hides
// under QK^T+softmax+PV (T14 async-STAGE split).
__global__ __launch_bounds__(512) void attn_kernel(const u16* __restrict__ Q,
                                                   const u16* __restrict__ KV,
                                                   const int* __restrict__ mask,
                                                   u16* __restrict__ O) {
  __shared__ u16 Ks[2][64 * 64];
  __shared__ u16 Vt[2][64 * 64];       // Vt[d][kv], slot-swizzled
  __shared__ float smask[2][64];

  const int tid = threadIdx.x;
  const int lane = tid & 63;
  const int wid = tid >> 6;            // 0..7
  const int l16 = lane & 15;
  const int kq = lane >> 4;            // 0..3
  const int bg = blockIdx.y;
  const int b = bg >> 2;               // / KVH
  const int g = bg & 3;
  const int h = g * REP_ + (wid & 3);
  const int q0 = blockIdx.x * 32 + (wid >> 2) * 16;

  // staging geometry (fixed per thread)
  const int krow = tid >> 3;           // K: row this thread stages
  const int kslot = tid & 7;
  const int vkvr = tid >> 3;           // V: kv row this thread stages
  const int vdc = (tid & 7) * 8;       // 8 d elems
  const u16* kv_base = KV + (size_t)b * S_ * KVD2_ + g * HD_;

  // V reg load (issue FIRST so later vmcnt for vwrite leaves K lds in flight)
  auto vload = [&](int kv0) -> uint4 {
    return *reinterpret_cast<const uint4*>(kv_base + (size_t)(kv0 + vkvr) * KVD2_ + KVD_ + vdc);
  };
  auto kstage = [&](int buf, int kv0) {
    __builtin_amdgcn_global_load_lds(
        (gvp)(kv_base + (size_t)(kv0 + krow) * KVD2_ + swz64(krow, kslot) * 8),
        (lvp)(&Ks[buf][tid * 8]), 16, 0, 0);
  };
  auto vwrite = [&](int buf, uint4 va) {
    const uint32_t vv[4] = {va.x, va.y, va.z, va.w};
    const int sl = vkvr >> 3;
    const int wv = vkvr & 7;
    u16* vt = &Vt[buf][0];
#pragma unroll
    for (int j = 0; j < 4; ++j) {
      const int d0 = vdc + 2 * j;
      const int d1 = d0 + 1;
      vt[d0 * 64 + swz64(d0, sl) * 8 + wv] = (u16)(vv[j] & 0xffffu);
      vt[d1 * 64 + swz64(d1, sl) * 8 + wv] = (u16)(vv[j] >> 16);
    }
  };

  // Q B-frags (rows of Q): lane holds Q[q0+l16][c*32 + kq*8 + j]
  s16x8 qf[2];
  {
    const u16* qp = Q + (size_t)(b * S_ + q0 + l16) * D_ + h * HD_ + kq * 8;
    qf[0] = *reinterpret_cast<const s16x8*>(qp);
    qf[1] = *reinterpret_cast<const s16x8*>(qp + 32);
  }

  // prologue: stage tile 0 into buf 0 (latency exposed once)
  {
    const uint4 v0 = vload(0);
    kstage(0, 0);
    int mr = 0;
    if (tid < 64) mr = mask[b * S_ + tid];
    vwrite(0, v0);
    if (tid < 64) smask[0][tid] = mr ? 0.f : -1e30f;
  }

  float m_run = -1e30f, l_run = 0.f;
  f32x4 acc[4] = {};                   // O^T: lane holds O^T[m*16+kq*4+r][q=l16]
  const float Cs = 0.18033688011112042f;  // SCALE * log2(e)
  int cur = 0;

  for (int t = 0; t < NT_; ++t) {
    __syncthreads();                   // buf[cur] ready; buf[cur^1] free to overwrite
    const bool pf = (t + 1 < NT_);
    uint4 vreg;
    int mreg = 0;
    if (pf) {
      vreg = vload((t + 1) * 64);      // V regs first
      kstage(cur ^ 1, (t + 1) * 64);   // then K direct-to-LDS
      if (tid < 64) mreg = mask[b * S_ + (t + 1) * 64 + tid];
    }

    const u16* ks = &Ks[cur][0];
    const u16* vt = &Vt[cur][0];
    const float* sm = &smask[cur][0];

    // S^T = K·Q^T: sc[n] holds rows n*16+kq*4+r (kv), col l16 (q)
    f32x4 sc[4];
#pragma unroll
    for (int n = 0; n < 4; ++n) {
      f32x4 s = {0.f, 0.f, 0.f, 0.f};
#pragma unroll
      for (int c = 0; c < 2; ++c) {
        const s16x8 kf = *frag64(ks, n * 16 + l16, c * 4 + kq);
        s = __builtin_amdgcn_mfma_f32_16x16x32_bf16(kf, qf[c], s, 0, 0, 0);
      }
      sc[n] = s;
    }

    // scale + mask in log2 domain; per-lane max over 16 + 2 shfl across kq
    float tm = -1e30f;
#pragma unroll
    for (int n = 0; n < 4; ++n) {
      const f32x4 mk = *reinterpret_cast<const f32x4*>(&sm[n * 16 + kq * 4]);
#pragma unroll
      for (int r = 0; r < 4; ++r) {
        sc[n][r] = sc[n][r] * Cs + mk[r];
        tm = fmaxf(tm, sc[n][r]);
      }
    }
    tm = fmaxf(tm, __shfl_xor(tm, 16));
    tm = fmaxf(tm, __shfl_xor(tm, 32));

    // defer-rescale (T13): only rescale when tile max grew past threshold
    if (!__all(tm <= m_run + 8.0f)) {
      const float mnew = fmaxf(m_run, tm);
      const float fac = exp2f(m_run - mnew);
      m_run = mnew;
      l_run *= fac;
#pragma unroll
      for (int m = 0; m < 4; ++m)
#pragma unroll
        for (int r = 0; r < 4; ++r) acc[m][r] *= fac;
    }

    float rs = 0.f;
#pragma unroll
    for (int n = 0; n < 4; ++n)
#pragma unroll
      for (int r = 0; r < 4; ++r) {
        const float p = exp2f(sc[n][r] - m_run);
        sc[n][r] = p;
        rs += p;
      }
    rs += __shfl_xor(rs, 16);
    rs += __shfl_xor(rs, 32);
    l_run += rs;

    // pack P to bf16 pairs: pk[n][hh] = (p[n][2hh], p[n][2hh+1])
    uint32_t pk[4][2];
#pragma unroll
    for (int n = 0; n < 4; ++n) {
      asm("v_cvt_pk_bf16_f32 %0, %1, %2" : "=v"(pk[n][0]) : "v"(sc[n][0]), "v"(sc[n][1]));
      asm("v_cvt_pk_bf16_f32 %0, %1, %2" : "=v"(pk[n][1]) : "v"(sc[n][2]), "v"(sc[n][3]));
    }
    // exchange: B-frag (rows of P) word w of frag c comes from
    // pk[2c + (kq>>1)][w&1] of lane ((kq&1)*2 + (w>>1))*16 + l16.
    const int srcA = ((kq & 1) * 2) * 16 + l16;
    const int srcB = srcA + 16;
    uint32_t bw[2][4];
#pragma unroll
    for (int c = 0; c < 2; ++c) {
#pragma unroll
      for (int w = 0; w < 4; ++w) {
        const int src = (w < 2) ? srcA : srcB;
        const uint32_t lo = __shfl(pk[2 * c][w & 1], src);
        const uint32_t hi = __shfl(pk[2 * c + 1][w & 1], src);
        bw[c][w] = (kq & 2) ? hi : lo;
      }
    }
    union { uint32_t u[4]; s16x8 v; } pf0, pf1;
#pragma unroll
    for (int w = 0; w < 4; ++w) { pf0.u[w] = bw[0][w]; pf1.u[w] = bw[1][w]; }

    // O^T += V^T · P^T : mfma(Vt-frag, P-row-frag)
#pragma unroll
    for (int m = 0; m < 4; ++m) {
      const s16x8 vf0 = *frag64(vt, m * 16 + l16, kq);
      const s16x8 vf1 = *frag64(vt, m * 16 + l16, 4 + kq);
      acc[m] = __builtin_amdgcn_mfma_f32_16x16x32_bf16(vf0, pf0.v, acc[m], 0, 0, 0);
      acc[m] = __builtin_amdgcn_mfma_f32_16x16x32_bf16(vf1, pf1.v, acc[m], 0, 0, 0);
    }

    // late STAGE-WRITE: V regs + mask into buf^1 (vmcnt waits only on vreg)
    if (pf) {
      vwrite(cur ^ 1, vreg);
      if (tid < 64) smask[cur ^ 1][tid] = mreg ? 0.f : -1e30f;
    }
    cur ^= 1;
  }

  // normalize + store O^T -> O (bf16, token-major [BS][D]); 4x 8B stores
  const float rl = 1.0f / l_run;
  u16* op = O + (size_t)(b * S_ + q0 + l16) * D_ + h * HD_ + kq * 4;
#pragma unroll
  for (int m = 0; m < 4; ++m) {
    uint2 o;
    o.x = (uint32_t)f2b(acc[m][0] * rl) | ((uint32_t)f2b(acc[m][1] * rl) << 16);
    o.y = (uint32_t)f2b(acc[m][2] * rl) | ((uint32_t)f2b(acc[m][3] * rl) << 16);
    *reinterpret_cast<uint2*>(op + m * 16) = o;
  }
}

// ---------------- launch ----------------
extern "C" void kernel_launch(void* const* d_in, const int* in_sizes, int n_in,
                              void* d_out, int out_size, void* d_ws, size_t ws_size,
                              hipStream_t stream) {
  const float* x = (const float*)d_in[0];
  const int* mask = (const int*)d_in[1];
  const float* Wq = (const float*)d_in[2];
  const float* Wk = (const float*)d_in[3];
  const float* Wv = (const float*)d_in[4];
  const float* Wo = (const float*)d_in[5];

  char* w = (char*)d_ws;
  u16* xb = (u16*)w;   w += (size_t)BS_ * D_ * 2;
  u16* Wqb = (u16*)w;  w += (size_t)D_ * D_ * 2;
  u16* Wkvb = (u16*)w; w += (size_t)KVD2_ * D_ * 2;   // Wk rows then Wv rows: 512 x 1024
  u16* Wob = (u16*)w;  w += (size_t)D_ * D_ * 2;
  u16* Qw = (u16*)w;   w += (size_t)BS_ * D_ * 2;
  u16* KVw = (u16*)w;  w += (size_t)BS_ * KVD2_ * 2;  // [token][ K(256) | V(256) ]
  u16* AOw = (u16*)w;  w += (size_t)BS_ * D_ * 2;

  auto cvt = [&](const float* src, u16* dst, int n) {
    int n4 = n / 4;
    cvt_kernel<<<dim3((n4 + 255) / 256), dim3(256), 0, stream>>>(src, dst, n4);
  };
  cvt(x, xb, BS_ * D_);
  cvt(Wq, Wqb, D_ * D_);
  cvt(Wk, Wkvb, KVD_ * D_);
  cvt(Wv, Wkvb + (size_t)KVD_ * D_, KVD_ * D_);
  cvt(Wo, Wob, D_ * D_);

  // Q projection: (4096x1024) = xb * Wq^T
  gemm_bt<1><<<dim3(D_ / 128, BS_ / 128), dim3(256), 0, stream>>>(xb, Wqb, Qw, BS_, D_, D_);
  // fused K|V projection: (4096x512)
  gemm_bt<1><<<dim3(KVD2_ / 128, BS_ / 128), dim3(256), 0, stream>>>(xb, Wkvb, KVw, BS_, KVD2_, D_);
  // attention: (S/32, B*KVH) blocks of 8 waves
  attn_kernel<<<dim3(S_ / 32, B_ * KVH_), dim3(512), 0, stream>>>(Qw, KVw, mask, AOw);
  // output projection -> fp32 d_out
  gemm_bt<0><<<dim3(D_ / 128, BS_ / 128), dim3(256), 0, stream>>>(AOw, Wob, (float*)d_out, BS_, D_, D_);
}

// Round 7
// 168.561 us; speedup vs baseline: 1.5671x; 1.0931x over previous
//
#include <hip/hip_runtime.h>
#include <hip/hip_bf16.h>
#include <stdint.h>

// Problem constants (GroupedQueryAttention: B=2,S=2048,D=1024,H=16,KVH=4)
#define B_    2
#define S_    2048
#define D_    1024
#define H_    16
#define KVH_  4
#define HD_   64
#define REP_  4
#define SCALE_ 0.125f
#define BS_   (B_ * S_)        // 4096 tokens
#define KVD_  (KVH_ * HD_)     // 256
#define QKVS_ 1536             // fused QKV row stride: Q(1024) | K(256) | V(256)
#define NT_   (S_ / 64)        // 32 KV tiles

typedef unsigned short u16;
typedef short s16x8 __attribute__((ext_vector_type(8)));
typedef float f32x4 __attribute__((ext_vector_type(4)));

typedef const __attribute__((address_space(1))) void* gvp;
typedef __attribute__((address_space(3))) void* lvp;

__device__ __forceinline__ u16 f2b(float f) {  // RNE f32->bf16 (finite inputs)
  uint32_t u = __float_as_uint(f);
  u += 0x7fffu + ((u >> 16) & 1u);
  return (u16)(u >> 16);
}

// XOR swizzle for 64-elem-wide bf16 LDS rows (128B = 8 x 16B slots).
__device__ __forceinline__ int swz64(int row, int slot) {
  return slot ^ (row & 7) ^ ((row >> 3) & 7);
}
__device__ __forceinline__ const s16x8* frag64(const u16* base, int row, int slot) {
  return reinterpret_cast<const s16x8*>(base + row * 64 + swz64(row, slot) * 8);
}

// ---------------- f32 -> bf16 conversion, x4 vectorized ----------------
__global__ void cvt_kernel(const float* __restrict__ in, u16* __restrict__ out, int n4) {
  int i = blockIdx.x * blockDim.x + threadIdx.x;
  if (i >= n4) return;
  const float4 v = reinterpret_cast<const float4*>(in)[i];
  uint2 o;
  o.x = (uint32_t)f2b(v.x) | ((uint32_t)f2b(v.y) << 16);
  o.y = (uint32_t)f2b(v.z) | ((uint32_t)f2b(v.w) << 16);
  reinterpret_cast<uint2*>(out)[i] = o;
}

// ---------------- bf16 GEMM, C = A(MxK) * B(NxK)^T  (both K-contiguous) ----------------
// 128x128 tile, BK=32, 4 waves, 4x4 16x16x32 MFMA acc per wave. m97 structure.
template <int OUT_BF16>
__global__ __launch_bounds__(256) void gemm_bt(const u16* __restrict__ A,
                                               const u16* __restrict__ Bw,
                                               void* __restrict__ Cout,
                                               int M, int N, int K) {
  __shared__ u16 As[128 * 32];
  __shared__ u16 Bs[128 * 32];
  const int tid = threadIdx.x;
  const int lane = tid & 63;
  const int wid = tid >> 6;
  const int l16 = lane & 15;
  const int kq = lane >> 4;
  const int bm = blockIdx.y * 128;
  const int bn = blockIdx.x * 128;
  const int wr = (wid >> 1) * 64;
  const int wc = (wid & 1) * 64;

  f32x4 acc[4][4] = {};

  for (int kt = 0; kt < K; kt += 32) {
    __syncthreads();
#pragma unroll
    for (int i = 0; i < 2; ++i) {
      const int e = (i * 256 + tid) * 8;   // element index in [128][32] tile
      const int row = e >> 5;
      const int col = e & 31;
      __builtin_amdgcn_global_load_lds((gvp)(A + (size_t)(bm + row) * K + kt + col),
                                       (lvp)(&As[e]), 16, 0, 0);
      __builtin_amdgcn_global_load_lds((gvp)(Bw + (size_t)(bn + row) * K + kt + col),
                                       (lvp)(&Bs[e]), 16, 0, 0);
    }
    __syncthreads();

    s16x8 af[4], bfr[4];
#pragma unroll
    for (int m = 0; m < 4; ++m)
      af[m] = *reinterpret_cast<const s16x8*>(&As[(wr + m * 16 + l16) * 32 + kq * 8]);
#pragma unroll
    for (int n = 0; n < 4; ++n)
      bfr[n] = *reinterpret_cast<const s16x8*>(&Bs[(wc + n * 16 + l16) * 32 + kq * 8]);
#pragma unroll
    for (int m = 0; m < 4; ++m)
#pragma unroll
      for (int n = 0; n < 4; ++n)
        acc[m][n] = __builtin_amdgcn_mfma_f32_16x16x32_bf16(af[m], bfr[n], acc[m][n], 0, 0, 0);
  }

  // C/D layout: col = lane&15, row = (lane>>4)*4 + r  (m89-verified)
#pragma unroll
  for (int m = 0; m < 4; ++m) {
    const int row0 = bm + wr + m * 16 + kq * 4;
#pragma unroll
    for (int n = 0; n < 4; ++n) {
      const int col = bn + wc + n * 16 + l16;
#pragma unroll
      for (int r = 0; r < 4; ++r) {
        if (OUT_BF16) {
          ((u16*)Cout)[(size_t)(row0 + r) * N + col] = f2b(acc[m][n][r]);
        } else {
          ((float*)Cout)[(size_t)(row0 + r) * N + col] = acc[m][n][r];
        }
      }
    }
  }
}

// ---------------- flash attention (GQA): swapped-QK^T, 32 q-rows/wave ----------------
// grid: (S/32, B*KVH). 256 thr = 4 waves; wave w = head g*4+w, q rows
// [q0, q0+32) as two 16-col groups. K/V staged once per tile, shared by all
// waves; each K/V fragment read feeds 2 MFMA (one per q-group) -> halved
// LDS-read volume per FLOP vs 16 q/wave. Double-buffered async staging (T14).
__global__ __launch_bounds__(256) void attn_kernel(const u16* __restrict__ QKV,
                                                   const int* __restrict__ mask,
                                                   u16* __restrict__ O) {
  __shared__ u16 Ks[2][64 * 64];
  __shared__ u16 Vt[2][64 * 64];       // Vt[d][kv], slot-swizzled
  __shared__ float smask[2][64];

  const int tid = threadIdx.x;
  const int lane = tid & 63;
  const int wid = tid >> 6;            // 0..3 = head within group
  const int l16 = lane & 15;
  const int kq = lane >> 4;            // 0..3
  const int bg = blockIdx.y;
  const int b = bg >> 2;               // / KVH
  const int g = bg & 3;
  const int h = g * REP_ + wid;
  const int q0 = blockIdx.x * 32;

  // staging geometry (fixed per thread)
  const int vkvr = tid >> 2;           // V: kv row this thread stages
  const int vdc = (tid & 3) * 16;      // 16 d elems (2 x uint4)
  const u16* kv_base = QKV + (size_t)b * S_ * QKVS_ + D_ + g * HD_;  // K cols

  auto vload = [&](int kv0, uint4* va) {
    const u16* p = kv_base + (size_t)(kv0 + vkvr) * QKVS_ + KVD_ + vdc;  // V = K + 256
    va[0] = *reinterpret_cast<const uint4*>(p);
    va[1] = *reinterpret_cast<const uint4*>(p + 8);
  };
  auto kstage = [&](int buf, int kv0) {
#pragma unroll
    for (int i = 0; i < 2; ++i) {
      const int e = (i * 256 + tid) * 8;
      const int row = e >> 6;
      const int slot = (e >> 3) & 7;
      __builtin_amdgcn_global_load_lds(
          (gvp)(kv_base + (size_t)(kv0 + row) * QKVS_ + swz64(row, slot) * 8),
          (lvp)(&Ks[buf][e]), 16, 0, 0);
    }
  };
  auto vwrite = [&](int buf, const uint4* va) {
    const int sl = vkvr >> 3;
    const int wv = vkvr & 7;
    u16* vt = &Vt[buf][0];
#pragma unroll
    for (int i = 0; i < 2; ++i) {
      const uint32_t vv[4] = {va[i].x, va[i].y, va[i].z, va[i].w};
#pragma unroll
      for (int j = 0; j < 4; ++j) {
        const int d0 = vdc + i * 8 + 2 * j;
        const int d1 = d0 + 1;
        vt[d0 * 64 + swz64(d0, sl) * 8 + wv] = (u16)(vv[j] & 0xffffu);
        vt[d1 * 64 + swz64(d1, sl) * 8 + wv] = (u16)(vv[j] >> 16);
      }
    }
  };

  // Q B-frags: qf[g2][c] = Q[q0+g2*16+l16][c*32+kq*8..], group g2 in {0,1}
  s16x8 qf[2][2];
#pragma unroll
  for (int g2 = 0; g2 < 2; ++g2) {
    const u16* qp = QKV + (size_t)(b * S_ + q0 + g2 * 16 + l16) * QKVS_ + h * HD_ + kq * 8;
    qf[g2][0] = *reinterpret_cast<const s16x8*>(qp);
    qf[g2][1] = *reinterpret_cast<const s16x8*>(qp + 32);
  }

  // prologue: stage tile 0 into buf 0
  {
    uint4 v0[2];
    vload(0, v0);
    kstage(0, 0);
    int mr = 0;
    if (tid < 64) mr = mask[b * S_ + tid];
    vwrite(0, v0);
    if (tid < 64) smask[0][tid] = mr ? 0.f : -1e30f;
  }

  float m_run[2] = {-1e30f, -1e30f}, l_run[2] = {0.f, 0.f};
  f32x4 acc[2][4] = {};                // O^T per group: row d=m*16+kq*4+r, col q=l16
  const float Cs = 0.18033688011112042f;  // SCALE * log2(e)
  int cur = 0;

  for (int t = 0; t < NT_; ++t) {
    __syncthreads();                   // buf[cur] ready; buf[cur^1] free
    const bool pfch = (t + 1 < NT_);
    uint4 vreg[2];
    int mreg = 0;
    if (pfch) {
      vload((t + 1) * 64, vreg);       // V regs first
      kstage(cur ^ 1, (t + 1) * 64);   // then K direct-to-LDS
      if (tid < 64) mreg = mask[b * S_ + (t + 1) * 64 + tid];
    }

    const u16* ks = &Ks[cur][0];
    const u16* vt = &Vt[cur][0];
    const float* sm = &smask[cur][0];

    // S^T = K·Q^T for both q-groups; K frag read shared
    f32x4 sc[2][4];
#pragma unroll
    for (int n = 0; n < 4; ++n) {
      f32x4 s0 = {0.f, 0.f, 0.f, 0.f};
      f32x4 s1 = {0.f, 0.f, 0.f, 0.f};
#pragma unroll
      for (int c = 0; c < 2; ++c) {
        const s16x8 kf = *frag64(ks, n * 16 + l16, c * 4 + kq);
        s0 = __builtin_amdgcn_mfma_f32_16x16x32_bf16(kf, qf[0][c], s0, 0, 0, 0);
        s1 = __builtin_amdgcn_mfma_f32_16x16x32_bf16(kf, qf[1][c], s1, 0, 0, 0);
      }
      sc[0][n] = s0;
      sc[1][n] = s1;
    }

    // mask values shared by both groups (depend only on kv row)
    f32x4 mk[4];
#pragma unroll
    for (int n = 0; n < 4; ++n)
      mk[n] = *reinterpret_cast<const f32x4*>(&sm[n * 16 + kq * 4]);

    union { uint32_t u[4]; s16x8 v; } pf[2][2];
#pragma unroll
    for (int g2 = 0; g2 < 2; ++g2) {
      // scale + mask in log2 domain; per-lane max + 2 shfl across kq
      float tm = -1e30f;
#pragma unroll
      for (int n = 0; n < 4; ++n)
#pragma unroll
        for (int r = 0; r < 4; ++r) {
          sc[g2][n][r] = sc[g2][n][r] * Cs + mk[n][r];
          tm = fmaxf(tm, sc[g2][n][r]);
        }
      tm = fmaxf(tm, __shfl_xor(tm, 16));
      tm = fmaxf(tm, __shfl_xor(tm, 32));

      // defer-rescale (T13)
      if (!__all(tm <= m_run[g2] + 8.0f)) {
        const float mnew = fmaxf(m_run[g2], tm);
        const float fac = exp2f(m_run[g2] - mnew);
        m_run[g2] = mnew;
        l_run[g2] *= fac;
#pragma unroll
        for (int m = 0; m < 4; ++m)
#pragma unroll
          for (int r = 0; r < 4; ++r) acc[g2][m][r] *= fac;
      }

      float rs = 0.f;
#pragma unroll
      for (int n = 0; n < 4; ++n)
#pragma unroll
        for (int r = 0; r < 4; ++r) {
          const float p = exp2f(sc[g2][n][r] - m_run[g2]);
          sc[g2][n][r] = p;
          rs += p;
        }
      rs += __shfl_xor(rs, 16);
      rs += __shfl_xor(rs, 32);
      l_run[g2] += rs;

      // pack P to bf16 pairs
      uint32_t pk[4][2];
#pragma unroll
      for (int n = 0; n < 4; ++n) {
        asm("v_cvt_pk_bf16_f32 %0, %1, %2" : "=v"(pk[n][0]) : "v"(sc[g2][n][0]), "v"(sc[g2][n][1]));
        asm("v_cvt_pk_bf16_f32 %0, %1, %2" : "=v"(pk[n][1]) : "v"(sc[g2][n][2]), "v"(sc[g2][n][3]));
      }
      // exchange: frag c word w <- pk[2c+(kq>>1)][w&1] of lane ((kq&1)*2+(w>>1))*16+l16
      const int srcA = ((kq & 1) * 2) * 16 + l16;
      const int srcB = srcA + 16;
#pragma unroll
      for (int c = 0; c < 2; ++c)
#pragma unroll
        for (int w = 0; w < 4; ++w) {
          const int src = (w < 2) ? srcA : srcB;
          const uint32_t lo = __shfl(pk[2 * c][w & 1], src);
          const uint32_t hi = __shfl(pk[2 * c + 1][w & 1], src);
          pf[g2][c].u[w] = (kq & 2) ? hi : lo;
        }
    }

    // O^T += V^T·P^T; V frag read shared by both groups
#pragma unroll
    for (int m = 0; m < 4; ++m) {
      const s16x8 vf0 = *frag64(vt, m * 16 + l16, kq);
      const s16x8 vf1 = *frag64(vt, m * 16 + l16, 4 + kq);
      acc[0][m] = __builtin_amdgcn_mfma_f32_16x16x32_bf16(vf0, pf[0][0].v, acc[0][m], 0, 0, 0);
      acc[0][m] = __builtin_amdgcn_mfma_f32_16x16x32_bf16(vf1, pf[0][1].v, acc[0][m], 0, 0, 0);
      acc[1][m] = __builtin_amdgcn_mfma_f32_16x16x32_bf16(vf0, pf[1][0].v, acc[1][m], 0, 0, 0);
      acc[1][m] = __builtin_amdgcn_mfma_f32_16x16x32_bf16(vf1, pf[1][1].v, acc[1][m], 0, 0, 0);
    }

    // late STAGE-WRITE: V regs + mask into buf^1
    if (pfch) {
      vwrite(cur ^ 1, vreg);
      if (tid < 64) smask[cur ^ 1][tid] = mreg ? 0.f : -1e30f;
    }
    cur ^= 1;
  }

  // normalize + store O^T -> O (bf16, token-major [BS][D])
#pragma unroll
  for (int g2 = 0; g2 < 2; ++g2) {
    const float rl = 1.0f / l_run[g2];
    u16* op = O + (size_t)(b * S_ + q0 + g2 * 16 + l16) * D_ + h * HD_ + kq * 4;
#pragma unroll
    for (int m = 0; m < 4; ++m) {
      uint2 o;
      o.x = (uint32_t)f2b(acc[g2][m][0] * rl) | ((uint32_t)f2b(acc[g2][m][1] * rl) << 16);
      o.y = (uint32_t)f2b(acc[g2][m][2] * rl) | ((uint32_t)f2b(acc[g2][m][3] * rl) << 16);
      *reinterpret_cast<uint2*>(op + m * 16) = o;
    }
  }
}

// ---------------- launch ----------------
extern "C" void kernel_launch(void* const* d_in, const int* in_sizes, int n_in,
                              void* d_out, int out_size, void* d_ws, size_t ws_size,
                              hipStream_t stream) {
  const float* x = (const float*)d_in[0];
  const int* mask = (const int*)d_in[1];
  const float* Wq = (const float*)d_in[2];
  const float* Wk = (const float*)d_in[3];
  const float* Wv = (const float*)d_in[4];
  const float* Wo = (const float*)d_in[5];

  char* w = (char*)d_ws;
  u16* xb = (u16*)w;    w += (size_t)BS_ * D_ * 2;
  u16* Wqkvb = (u16*)w; w += (size_t)QKVS_ * D_ * 2;  // Wq(1024) | Wk(256) | Wv(256) rows
  u16* Wob = (u16*)w;   w += (size_t)D_ * D_ * 2;
  u16* QKVw = (u16*)w;  w += (size_t)BS_ * QKVS_ * 2; // [token][ Q | K | V ]
  u16* AOw = (u16*)w;   w += (size_t)BS_ * D_ * 2;

  auto cvt = [&](const float* src, u16* dst, int n) {
    int n4 = n / 4;
    cvt_kernel<<<dim3((n4 + 255) / 256), dim3(256), 0, stream>>>(src, dst, n4);
  };
  cvt(x, xb, BS_ * D_);
  cvt(Wq, Wqkvb, D_ * D_);
  cvt(Wk, Wqkvb + (size_t)D_ * D_, KVD_ * D_);
  cvt(Wv, Wqkvb + (size_t)(D_ + KVD_) * D_, KVD_ * D_);
  cvt(Wo, Wob, D_ * D_);

  // fused QKV projection: (4096 x 1536) = xb * Wqkv^T
  gemm_bt<1><<<dim3(QKVS_ / 128, BS_ / 128), dim3(256), 0, stream>>>(xb, Wqkvb, QKVw, BS_, QKVS_, D_);
  // attention: (S/32, B*KVH) blocks of 4 waves, 32 q-rows/wave
  attn_kernel<<<dim3(S_ / 32, B_ * KVH_), dim3(256), 0, stream>>>(QKVw, mask, AOw);
  // output projection -> fp32 d_out
  gemm_bt<0><<<dim3(D_ / 128, BS_ / 128), dim3(256), 0, stream>>>(AOw, Wob, (float*)d_out, BS_, D_, D_);
}